// Round 1
// 669.977 us; speedup vs baseline: 1.0013x; 1.0013x over previous
//
#include <hip/hip_runtime.h>
#include <cstdint>

#define NN 100000
#define EE 1600000
#define GG 64
#define FIN 128
#define HC 256      // H*C for layer 1
#define NC 10

typedef short v8s __attribute__((ext_vector_type(8)));
typedef float v4f __attribute__((ext_vector_type(4)));

static __device__ __forceinline__ float lrelu(float x) { return x > 0.f ? x : 0.2f * x; }
static __device__ __forceinline__ float bf2f(unsigned short b) {
  return __uint_as_float(((unsigned int)b) << 16);
}
static __device__ __forceinline__ unsigned short f2bf(float f) {
  unsigned int u = __float_as_uint(f);
  unsigned int r = (u + 0x7FFFu + ((u >> 16) & 1u)) >> 16;
  return (unsigned short)r;
}
static __device__ __forceinline__ void unpack2(unsigned int u, float& f0, float& f1) {
  f0 = __uint_as_float(u << 16);          // even channel (lo ushort)
  f1 = __uint_as_float(u & 0xFFFF0000u);  // odd channel (hi ushort)
}

// ---------------- prepx: x -> bf16 (streamed) + zero counts ----------------
__global__ __launch_bounds__(256) void k_prepx(const float* __restrict__ x,
                                               unsigned short* __restrict__ xb,
                                               unsigned int* __restrict__ counts) {
  const int idx = blockIdx.x * 256 + threadIdx.x;
  const int i4 = idx * 4;                       // 12500*256*4 == 12.8M exact
  float4 v = *(const float4*)(x + i4);
  ushort4 u;
  u.x = f2bf(v.x); u.y = f2bf(v.y); u.z = f2bf(v.z); u.w = f2bf(v.w);
  *(ushort4*)(xb + i4) = u;
  if (idx < NN) counts[idx] = 0u;
}

// ---------------- prep: W1 -> bf16 transposed [n][k] ----------------
__global__ void k_prep(const float* __restrict__ W1, unsigned short* __restrict__ W1tg) {
  const int b = blockIdx.x, t = threadIdx.x;
  if (t < 128) W1tg[b * 128 + t] = f2bf(W1[t * HC + b]);
}

// ---------------- prep: W2 -> bf16 hi/lo split, transposed [32][256] ----------------
// hi+lo split keeps GEMM2 at ~f32 precision through the bf16 MFMA path.
__global__ void k_prepw2(const float* __restrict__ W2,
                         unsigned short* __restrict__ W2thi,
                         unsigned short* __restrict__ W2tlo) {
  const int b = blockIdx.x;    // output channel 0..31
  const int t = threadIdx.x;   // k 0..255
  float w = W2[t * 32 + b];
  unsigned short hi = f2bf(w);
  W2thi[b * 256 + t] = hi;
  W2tlo[b * 256 + t] = f2bf(w - bf2f(hi));
}

// ---------------- GEMM1 (bf16 MFMA, LDS-free) + fused scores1 ----------------
// grid (1563, 2): 64 rows x 128-col half per block; 4 waves x 16 rows.
__global__ __launch_bounds__(256) void k_gemm1(const unsigned short* __restrict__ xb,
                                               const unsigned short* __restrict__ W1tg,
                                               const float* __restrict__ att_src1,
                                               const float* __restrict__ att_dst1,
                                               unsigned short* __restrict__ h1b,
                                               float* __restrict__ as1,
                                               float* __restrict__ ad1) {
  const int t = threadIdx.x;
  const int m0 = blockIdx.x * 64;
  const int n0 = blockIdx.y * 128;
  const int hb = blockIdx.y * 4;       // head base of this column half
  const int lane = t & 63;
  const int wm = t >> 6;               // wave -> m sub-tile
  const int ml = lane & 15;
  const int quad = lane >> 4;
  int row = m0 + wm * 16 + ml; if (row >= NN) row = NN - 1;
  v4f acc[8];
#pragma unroll
  for (int tt = 0; tt < 8; ++tt) acc[tt] = (v4f){0.f, 0.f, 0.f, 0.f};
#pragma unroll
  for (int kk = 0; kk < 4; ++kk) {
    const int k0 = kk * 32 + quad * 8;
    v8s a = *(const v8s*)(xb + (size_t)row * FIN + k0);
#pragma unroll
    for (int tt = 0; tt < 8; ++tt) {
      v8s b = *(const v8s*)(W1tg + (size_t)(n0 + tt * 16 + ml) * FIN + k0);
      acc[tt] = __builtin_amdgcn_mfma_f32_16x16x32_bf16(a, b, acc[tt], 0, 0, 0);
    }
  }
  // h1b store (C layout: row=quad*4+r, col=tt*16+ml)
#pragma unroll
  for (int tt = 0; tt < 8; ++tt) {
#pragma unroll
    for (int r = 0; r < 4; ++r) {
      int rg = m0 + wm * 16 + quad * 4 + r;
      if (rg < NN) h1b[(size_t)rg * HC + n0 + tt * 16 + ml] = f2bf(acc[tt][r]);
    }
  }
  // fused scores1: 4 heads of this half; lane partials over its 8 columns
  float ps[4][4], pd[4][4];
#pragma unroll
  for (int i = 0; i < 4; ++i)
#pragma unroll
    for (int r = 0; r < 4; ++r) { ps[i][r] = 0.f; pd[i][r] = 0.f; }
#pragma unroll
  for (int i = 0; i < 4; ++i) {
#pragma unroll
    for (int half = 0; half < 2; ++half) {
      const int tt = 2 * i + half;
      const float a_s = att_src1[(hb + i) * 32 + half * 16 + ml];
      const float a_d = att_dst1[(hb + i) * 32 + half * 16 + ml];
#pragma unroll
      for (int r = 0; r < 4; ++r) {
        ps[i][r] += acc[tt][r] * a_s;
        pd[i][r] += acc[tt][r] * a_d;
      }
    }
  }
#pragma unroll
  for (int i = 0; i < 4; ++i) {
#pragma unroll
    for (int r = 0; r < 4; ++r) {
      float s = ps[i][r], d = pd[i][r];
      s += __shfl_xor(s, 1, 64); s += __shfl_xor(s, 2, 64);
      s += __shfl_xor(s, 4, 64); s += __shfl_xor(s, 8, 64);
      d += __shfl_xor(d, 1, 64); d += __shfl_xor(d, 2, 64);
      d += __shfl_xor(d, 4, 64); d += __shfl_xor(d, 8, 64);
      ps[i][r] = s; pd[i][r] = d;
    }
  }
  if (ml == 0) {
#pragma unroll
    for (int r = 0; r < 4; ++r) {
      int rg = m0 + wm * 16 + quad * 4 + r;
      if (rg < NN) {
#pragma unroll
        for (int i = 0; i < 4; ++i) {
          as1[rg * 8 + hb + i] = ps[i][r];
          ad1[rg * 8 + hb + i] = pd[i][r];
        }
      }
    }
  }
}

// ---------------- CSR build ----------------
__global__ void k_count(const int* __restrict__ ei, int* __restrict__ counts) {
  int e = blockIdx.x * 256 + threadIdx.x;
  if (e < EE) atomicAdd(&counts[ei[EE + e]], 1);
}

__global__ void k_scan1(const int* __restrict__ counts, int* __restrict__ offs,
                        int* __restrict__ bsums) {
  __shared__ int s[256];
  const int t = threadIdx.x;
  const int i = blockIdx.x * 256 + t;
  int v = (i < NN) ? counts[i] : 0;
  s[t] = v;
  __syncthreads();
  for (int off = 1; off < 256; off <<= 1) {
    int tv = (t >= off) ? s[t - off] : 0;
    __syncthreads();
    s[t] += tv;
    __syncthreads();
  }
  if (i < NN) offs[i] = s[t] - v;
  if (t == 255) bsums[blockIdx.x] = s[255];
}

__global__ void k_scan2(int* __restrict__ bsums, int nb) {
  __shared__ int s[512];
  const int t = threadIdx.x;
  int v = (t < nb) ? bsums[t] : 0;
  s[t] = v;
  __syncthreads();
  for (int off = 1; off < 512; off <<= 1) {
    int tv = (t >= off) ? s[t - off] : 0;
    __syncthreads();
    s[t] += tv;
    __syncthreads();
  }
  if (t < nb) bsums[t] = s[t] - v;
}

__global__ void k_scan3(int* __restrict__ offs, const int* __restrict__ bsums,
                        int* __restrict__ cursor) {
  const int i = blockIdx.x * 256 + threadIdx.x;
  if (i < NN) {
    int v = offs[i] + bsums[i >> 8];
    offs[i] = v;
    cursor[i] = v;
  }
  if (i == 0) offs[NN] = EE;
}

// ---------------- scatter: pure CSR permutation (weights now recomputed in agg1) ----
__global__ void k_scatter(const int* __restrict__ ei, int* __restrict__ cursor,
                          int* __restrict__ esrc) {
  int e = blockIdx.x * 256 + threadIdx.x;
  if (e < EE) {
    int s = ei[e];
    int d = ei[EE + e];
    int p = atomicAdd(&cursor[d], 1);
    esrc[p] = s;
  }
}

// ---------------- agg1: wave-per-node gather + ELU, then MFMA GEMM2 + scores2 ------
// 4 nodes / 256-thread block. Gather loop is barrier-free: each lane owns 4
// channels, z is replicated within each 8-lane head group, edge weights are
// recomputed from as1[src] (f32, one broadcast 32B load + exp per edge).
// Epilogue: waves drop post-ELU rows into LDS as bf16 hi/lo split; wave 0 runs
// M=4 x N=32 x K=256 GEMM2 on the matrix pipe (3 split terms -> ~f32 accuracy)
// and the fused scores2 reduction.
__global__ __launch_bounds__(256) void k_agg1(const unsigned short* __restrict__ h1b,
                                              const float* __restrict__ as1,
                                              const float* __restrict__ ad1,
                                              const int* __restrict__ offs,
                                              const int* __restrict__ esrc,
                                              const float* __restrict__ b1,
                                              const unsigned short* __restrict__ W2thi,
                                              const unsigned short* __restrict__ W2tlo,
                                              const float* __restrict__ att_src2,
                                              const float* __restrict__ att_dst2,
                                              unsigned short* __restrict__ h2b,
                                              float* __restrict__ as2,
                                              float* __restrict__ ad2) {
  __shared__ __attribute__((aligned(16))) unsigned short o1hi[4][256];
  __shared__ __attribute__((aligned(16))) unsigned short o1lo[4][256];
  const int t = threadIdx.x;
  const int lane = t & 63;
  const int w = t >> 6;
  const int n0 = blockIdx.x * 4;       // NN = 25000*4 exactly
  const int n = n0 + w;
  const int head = lane >> 3;          // channels 4*lane.. -> head = lane>>3
  const uint2* __restrict__ h1u2 = (const uint2*)h1b;
  const int start = offs[n], end = offs[n + 1];
  const float adn = ad1[n * 8 + head];

  float z, a0, a1, a2, a3;
  {  // self loop
    float w0 = __expf(lrelu(as1[n * 8 + head] + adn));
    uint2 q = h1u2[(size_t)n * 64 + lane];
    float f0, f1, f2, f3; unpack2(q.x, f0, f1); unpack2(q.y, f2, f3);
    z = w0; a0 = w0 * f0; a1 = w0 * f1; a2 = w0 * f2; a3 = w0 * f3;
  }
  for (int base = start; base < end; base += 64) {
    const int cnt = min(64, end - base);
    int sreg = 0;
    if (lane < cnt) sreg = esrc[base + lane];
#pragma unroll 8
    for (int j = 0; j < cnt; ++j) {
      const int sj = __builtin_amdgcn_readlane(sreg, j);   // uniform -> SGPR base
      const float sc = as1[sj * 8 + head];                 // 32B broadcast line
      const uint2 q = h1u2[(size_t)sj * 64 + lane];        // full 512B row per wave
      const float wv = __expf(lrelu(sc + adn));
      float f0, f1, f2, f3; unpack2(q.x, f0, f1); unpack2(q.y, f2, f3);
      z += wv;
      a0 += wv * f0; a1 += wv * f1; a2 += wv * f2; a3 += wv * f3;
    }
  }
  // out1 = acc/z + b1, ELU; store hi/lo bf16 split to LDS (channels 4*lane..+3)
  {
    const float zi = 1.0f / (z + 1e-16f);
    const float4 bb = *(const float4*)(b1 + 4 * lane);
    float v0 = a0 * zi + bb.x;
    float v1 = a1 * zi + bb.y;
    float v2 = a2 * zi + bb.z;
    float v3 = a3 * zi + bb.w;
    v0 = v0 > 0.f ? v0 : (__expf(v0) - 1.0f);
    v1 = v1 > 0.f ? v1 : (__expf(v1) - 1.0f);
    v2 = v2 > 0.f ? v2 : (__expf(v2) - 1.0f);
    v3 = v3 > 0.f ? v3 : (__expf(v3) - 1.0f);
    ushort4 hh, ll;
    hh.x = f2bf(v0); hh.y = f2bf(v1); hh.z = f2bf(v2); hh.w = f2bf(v3);
    ll.x = f2bf(v0 - bf2f(hh.x));
    ll.y = f2bf(v1 - bf2f(hh.y));
    ll.z = f2bf(v2 - bf2f(hh.z));
    ll.w = f2bf(v3 - bf2f(hh.w));
    *(ushort4*)&o1hi[w][4 * lane] = hh;
    *(ushort4*)&o1lo[w][4 * lane] = ll;
  }
  __syncthreads();
  if (w == 0) {
    // GEMM2: rows = 4 nodes (A rows indexed by ml, duplicated beyond 3), cols = 32.
    const int ml = lane & 15;
    const int quad = lane >> 4;
    const int mr = ml & 3;               // rows 4..15 compute garbage C rows (ignored)
    v4f acc[2];
    acc[0] = (v4f){0.f, 0.f, 0.f, 0.f};
    acc[1] = (v4f){0.f, 0.f, 0.f, 0.f};
#pragma unroll
    for (int kk = 0; kk < 8; ++kk) {
      const int k0 = kk * 32 + quad * 8;
      v8s ah = *(const v8s*)&o1hi[mr][k0];
      v8s al = *(const v8s*)&o1lo[mr][k0];
#pragma unroll
      for (int tt = 0; tt < 2; ++tt) {
        v8s bh = *(const v8s*)(W2thi + (size_t)(tt * 16 + ml) * 256 + k0);
        v8s bl = *(const v8s*)(W2tlo + (size_t)(tt * 16 + ml) * 256 + k0);
        acc[tt] = __builtin_amdgcn_mfma_f32_16x16x32_bf16(ah, bh, acc[tt], 0, 0, 0);
        acc[tt] = __builtin_amdgcn_mfma_f32_16x16x32_bf16(al, bh, acc[tt], 0, 0, 0);
        acc[tt] = __builtin_amdgcn_mfma_f32_16x16x32_bf16(ah, bl, acc[tt], 0, 0, 0);
      }
    }
    // C layout: col = ml, row = quad*4 + r; valid nodes live in quad 0, r = 0..3
    if (quad == 0) {
      const float s0 = att_src2[ml], s1 = att_src2[16 + ml];
      const float d0 = att_dst2[ml], d1 = att_dst2[16 + ml];
#pragma unroll
      for (int r = 0; r < 4; ++r) {
        const int nn = n0 + r;
        const float h0 = acc[0][r], h1v = acc[1][r];
        h2b[(size_t)nn * 32 + ml] = f2bf(h0);
        h2b[(size_t)nn * 32 + 16 + ml] = f2bf(h1v);
        float ps = h0 * s0 + h1v * s1;
        float pd = h0 * d0 + h1v * d1;
        ps += __shfl_xor(ps, 1, 64); ps += __shfl_xor(ps, 2, 64);
        ps += __shfl_xor(ps, 4, 64); ps += __shfl_xor(ps, 8, 64);
        pd += __shfl_xor(pd, 1, 64); pd += __shfl_xor(pd, 2, 64);
        pd += __shfl_xor(pd, 4, 64); pd += __shfl_xor(pd, 8, 64);
        if (ml == 0) { as2[nn] = ps; ad2[nn] = pd; }
      }
    }
  }
}

// ---------------- agg2: wave-per-node, 4 edges/iter, uint loads ----------------
__global__ __launch_bounds__(256) void k_agg2(const unsigned short* __restrict__ h2b,
                                              const float* __restrict__ as2,
                                              const float* __restrict__ ad2,
                                              const int* __restrict__ offs,
                                              const int* __restrict__ esrc,
                                              const float* __restrict__ b2,
                                              float* __restrict__ h3) {
  const int t = threadIdx.x;
  const int lane = t & 63;
  const int wv = t >> 6;
  const int n = blockIdx.x * 4 + wv;     // NN = 25000*4 exactly
  const int col = lane & 15;
  const int slot = lane >> 4;
  const unsigned int* h2u = (const unsigned int*)h2b;
  const int start = offs[n], end = offs[n + 1];
  const float adn = ad2[n];
  float z = 0.f, acc0 = 0.f, acc1 = 0.f;
  if (slot == 0) {   // self loop counted once
    float w0 = __expf(lrelu(as2[n] + adn));
    unsigned int q = h2u[(size_t)n * 16 + col];
    float f0, f1; unpack2(q, f0, f1);
    z = w0; acc0 = w0 * f0; acc1 = w0 * f1;
  }
  for (int base = start; base < end; base += 64) {
    const int cnt = min(64, end - base);
    int sreg = 0; float wreg = 0.f;
    if (lane < cnt) {
      sreg = esrc[base + lane];
      wreg = __expf(lrelu(as2[sreg] + adn));
    }
    const int jmax = (cnt + 3) >> 2;
#pragma unroll 4
    for (int j = 0; j < jmax; ++j) {
      const int e = 4 * j + slot;
      int sj = __shfl(sreg, e, 64);      // per-lane src (bpermute)
      float wj = __shfl(wreg, e, 64);
      if (e < cnt) {
        unsigned int q = h2u[(size_t)sj * 16 + col];
        float f0, f1; unpack2(q, f0, f1);
        z += wj; acc0 += wj * f0; acc1 += wj * f1;
      }
    }
  }
  // combine the 4 slot groups
  acc0 += __shfl_xor(acc0, 16, 64); acc0 += __shfl_xor(acc0, 32, 64);
  acc1 += __shfl_xor(acc1, 16, 64); acc1 += __shfl_xor(acc1, 32, 64);
  z    += __shfl_xor(z, 16, 64);    z    += __shfl_xor(z, 32, 64);
  if (slot == 0) {
    const float zi = 1.0f / (z + 1e-16f);
    float2 bb = *(const float2*)(b2 + 2 * col);
    float2 o;
    o.x = acc0 * zi + bb.x;
    o.y = acc1 * zi + bb.y;
    *(float2*)(h3 + (size_t)n * 32 + 2 * col) = o;
  }
}

// ---------------- pool + final linear (fused) ----------------
__global__ __launch_bounds__(256) void k_poolfin(const float* __restrict__ h3,
                                                 const int* __restrict__ batch,
                                                 const float* __restrict__ Wlin,
                                                 const float* __restrict__ blin,
                                                 float* __restrict__ out) {
  __shared__ int bounds[2];
  __shared__ float red[8][33];
  __shared__ float mean[32];
  const int g = blockIdx.x;
  const int t = threadIdx.x;
  if (t < 2) {
    int target = g + t;
    int lo = 0, hi = NN;
    while (lo < hi) { int mid = (lo + hi) >> 1; if (batch[mid] < target) lo = mid + 1; else hi = mid; }
    bounds[t] = lo;
  }
  __syncthreads();
  const int lo = bounds[0], hi = bounds[1];
  const int rr = t >> 5, c = t & 31;
  float a = 0.f;
  for (int r = lo + rr; r < hi; r += 8) a += h3[(size_t)r * 32 + c];
  red[rr][c] = a;
  __syncthreads();
  if (rr == 0) {
    float s = 0.f;
#pragma unroll
    for (int i = 0; i < 8; ++i) s += red[i][c];
    float ct = (float)(hi - lo);
    ct = ct > 1.f ? ct : 1.f;
    mean[c] = s / ct;
  }
  __syncthreads();
  if (t < NC) {
    float acc = 0.f;
#pragma unroll
    for (int cc = 0; cc < 32; ++cc) acc += mean[cc] * Wlin[cc * NC + t];
    out[g * NC + t] = acc + blin[t];
  }
}

extern "C" void kernel_launch(void* const* d_in, const int* in_sizes, int n_in,
                              void* d_out, int out_size, void* d_ws, size_t ws_size,
                              hipStream_t stream) {
  const float* x        = (const float*)d_in[0];
  const int*   ei       = (const int*)d_in[1];
  const int*   batch    = (const int*)d_in[2];
  const float* W1       = (const float*)d_in[3];
  const float* att_src1 = (const float*)d_in[4];
  const float* att_dst1 = (const float*)d_in[5];
  const float* b1       = (const float*)d_in[6];
  const float* W2       = (const float*)d_in[7];
  const float* att_src2 = (const float*)d_in[8];
  const float* att_dst2 = (const float*)d_in[9];
  const float* b2       = (const float*)d_in[10];
  const float* Wlin     = (const float*)d_in[11];
  const float* blin     = (const float*)d_in[12];
  float* out = (float*)d_out;
  char* ws = (char*)d_ws;

  // workspace layout (bytes); peak ~98.1 MB (wt16 eliminated; h3 overlays xb)
  unsigned short* h1b   = (unsigned short*)(ws + 0);         // 51,200,000
  unsigned short* xb    = (unsigned short*)(ws + 51200000);  // 25,600,000 (dead after gemm1)
  float* h3     = (float*)(ws + 51200000);                   // 12,800,000 overlay on xb
  float* as1    = (float*)(ws + 76800000);                   // 3,200,000
  float* ad1    = (float*)(ws + 80000000);                   // 3,200,000
  int* counts   = (int*)(ws + 83200000);                     // 400,000
  int* offs     = (int*)(ws + 83600000);                     // 400,004 (+pad)
  int* cursor   = (int*)(ws + 84000256);                     // 400,000
  int* esrc     = (int*)(ws + 84400256);                     // 6,400,000
  int* bsums    = (int*)(ws + 90800256);                     // 2,048 (pad)
  unsigned short* h2b   = (unsigned short*)(ws + 90802304);  // 6,400,000
  float* as2    = (float*)(ws + 97202304);                   // 400,000
  float* ad2    = (float*)(ws + 97602304);                   // 400,000
  unsigned short* W1tg  = (unsigned short*)(ws + 98002304);  // 65,536
  unsigned short* W2thi = (unsigned short*)(ws + 98067840);  // 16,384
  unsigned short* W2tlo = (unsigned short*)(ws + 98084224);  // 16,384

  const int nb_scan = (NN + 255) / 256;  // 391

  k_prepx<<<12500, 256, 0, stream>>>(x, xb, (unsigned int*)counts);
  k_prep<<<256, 128, 0, stream>>>(W1, W1tg);
  k_prepw2<<<32, 256, 0, stream>>>(W2, W2thi, W2tlo);

  dim3 g1((NN + 63) / 64, 2);
  k_gemm1<<<g1, 256, 0, stream>>>(xb, W1tg, att_src1, att_dst1, h1b, as1, ad1);

  k_count<<<(EE + 255) / 256, 256, 0, stream>>>(ei, counts);
  k_scan1<<<nb_scan, 256, 0, stream>>>(counts, offs, bsums);
  k_scan2<<<1, 512, 0, stream>>>(bsums, nb_scan);
  k_scan3<<<nb_scan, 256, 0, stream>>>(offs, bsums, cursor);
  k_scatter<<<(EE + 255) / 256, 256, 0, stream>>>(ei, cursor, esrc);

  k_agg1<<<NN / 4, 256, 0, stream>>>(h1b, as1, ad1, offs, esrc, b1, W2thi, W2tlo,
                                     att_src2, att_dst2, h2b, as2, ad2);

  k_agg2<<<NN / 4, 256, 0, stream>>>(h2b, as2, ad2, offs, esrc, b2, h3);
  k_poolfin<<<GG, 256, 0, stream>>>(h3, batch, Wlin, blin, out);
}

// Round 2
// 635.957 us; speedup vs baseline: 1.0549x; 1.0535x over previous
//
#include <hip/hip_runtime.h>
#include <cstdint>

#define NN 100000
#define EE 1600000
#define GG 64
#define FIN 128
#define HC 256      // H*C for layer 1
#define NC 10

typedef short v8s __attribute__((ext_vector_type(8)));
typedef float v4f __attribute__((ext_vector_type(4)));

static __device__ __forceinline__ float lrelu(float x) { return x > 0.f ? x : 0.2f * x; }
static __device__ __forceinline__ float bf2f(unsigned short b) {
  return __uint_as_float(((unsigned int)b) << 16);
}
static __device__ __forceinline__ unsigned short f2bf(float f) {
  unsigned int u = __float_as_uint(f);
  unsigned int r = (u + 0x7FFFu + ((u >> 16) & 1u)) >> 16;
  return (unsigned short)r;
}
static __device__ __forceinline__ void unpack2(unsigned int u, float& f0, float& f1) {
  f0 = __uint_as_float(u << 16);          // even channel (lo ushort)
  f1 = __uint_as_float(u & 0xFFFF0000u);  // odd channel (hi ushort)
}

// ---------------- prepx: x -> bf16 (streamed) + fused edge count ----------------
// counts zeroed by hipMemsetAsync before this kernel; 3.2M threads >= EE.
__global__ __launch_bounds__(256) void k_prepx(const float* __restrict__ x,
                                               unsigned short* __restrict__ xb,
                                               const int* __restrict__ ei,
                                               int* __restrict__ counts) {
  const int idx = blockIdx.x * 256 + threadIdx.x;
  const int i4 = idx * 4;                       // 12500*256*4 == 12.8M exact
  float4 v = *(const float4*)(x + i4);
  ushort4 u;
  u.x = f2bf(v.x); u.y = f2bf(v.y); u.z = f2bf(v.z); u.w = f2bf(v.w);
  *(ushort4*)(xb + i4) = u;
  if (idx < EE) atomicAdd(&counts[ei[EE + idx]], 1);
}

// ---------------- prep: W1 -> bf16 transposed [n][k] ----------------
__global__ void k_prep(const float* __restrict__ W1, unsigned short* __restrict__ W1tg) {
  const int b = blockIdx.x, t = threadIdx.x;
  if (t < 128) W1tg[b * 128 + t] = f2bf(W1[t * HC + b]);
}

// ---------------- prep: W2 -> bf16 hi/lo split, transposed [32][256] ----------------
__global__ void k_prepw2(const float* __restrict__ W2,
                         unsigned short* __restrict__ W2thi,
                         unsigned short* __restrict__ W2tlo) {
  const int b = blockIdx.x;    // output channel 0..31
  const int t = threadIdx.x;   // k 0..255
  float w = W2[t * 32 + b];
  unsigned short hi = f2bf(w);
  W2thi[b * 256 + t] = hi;
  W2tlo[b * 256 + t] = f2bf(w - bf2f(hi));
}

// ---------------- GEMM1 (bf16 MFMA, LDS-free) + fused scores1 ----------------
__global__ __launch_bounds__(256) void k_gemm1(const unsigned short* __restrict__ xb,
                                               const unsigned short* __restrict__ W1tg,
                                               const float* __restrict__ att_src1,
                                               const float* __restrict__ att_dst1,
                                               unsigned short* __restrict__ h1b,
                                               float* __restrict__ as1,
                                               float* __restrict__ ad1) {
  const int t = threadIdx.x;
  const int m0 = blockIdx.x * 64;
  const int n0 = blockIdx.y * 128;
  const int hb = blockIdx.y * 4;       // head base of this column half
  const int lane = t & 63;
  const int wm = t >> 6;               // wave -> m sub-tile
  const int ml = lane & 15;
  const int quad = lane >> 4;
  int row = m0 + wm * 16 + ml; if (row >= NN) row = NN - 1;
  v4f acc[8];
#pragma unroll
  for (int tt = 0; tt < 8; ++tt) acc[tt] = (v4f){0.f, 0.f, 0.f, 0.f};
#pragma unroll
  for (int kk = 0; kk < 4; ++kk) {
    const int k0 = kk * 32 + quad * 8;
    v8s a = *(const v8s*)(xb + (size_t)row * FIN + k0);
#pragma unroll
    for (int tt = 0; tt < 8; ++tt) {
      v8s b = *(const v8s*)(W1tg + (size_t)(n0 + tt * 16 + ml) * FIN + k0);
      acc[tt] = __builtin_amdgcn_mfma_f32_16x16x32_bf16(a, b, acc[tt], 0, 0, 0);
    }
  }
  // h1b store (C layout: row=quad*4+r, col=tt*16+ml)
#pragma unroll
  for (int tt = 0; tt < 8; ++tt) {
#pragma unroll
    for (int r = 0; r < 4; ++r) {
      int rg = m0 + wm * 16 + quad * 4 + r;
      if (rg < NN) h1b[(size_t)rg * HC + n0 + tt * 16 + ml] = f2bf(acc[tt][r]);
    }
  }
  // fused scores1
  float ps[4][4], pd[4][4];
#pragma unroll
  for (int i = 0; i < 4; ++i)
#pragma unroll
    for (int r = 0; r < 4; ++r) { ps[i][r] = 0.f; pd[i][r] = 0.f; }
#pragma unroll
  for (int i = 0; i < 4; ++i) {
#pragma unroll
    for (int half = 0; half < 2; ++half) {
      const int tt = 2 * i + half;
      const float a_s = att_src1[(hb + i) * 32 + half * 16 + ml];
      const float a_d = att_dst1[(hb + i) * 32 + half * 16 + ml];
#pragma unroll
      for (int r = 0; r < 4; ++r) {
        ps[i][r] += acc[tt][r] * a_s;
        pd[i][r] += acc[tt][r] * a_d;
      }
    }
  }
#pragma unroll
  for (int i = 0; i < 4; ++i) {
#pragma unroll
    for (int r = 0; r < 4; ++r) {
      float s = ps[i][r], d = pd[i][r];
      s += __shfl_xor(s, 1, 64); s += __shfl_xor(s, 2, 64);
      s += __shfl_xor(s, 4, 64); s += __shfl_xor(s, 8, 64);
      d += __shfl_xor(d, 1, 64); d += __shfl_xor(d, 2, 64);
      d += __shfl_xor(d, 4, 64); d += __shfl_xor(d, 8, 64);
      ps[i][r] = s; pd[i][r] = d;
    }
  }
  if (ml == 0) {
#pragma unroll
    for (int r = 0; r < 4; ++r) {
      int rg = m0 + wm * 16 + quad * 4 + r;
      if (rg < NN) {
#pragma unroll
        for (int i = 0; i < 4; ++i) {
          as1[rg * 8 + hb + i] = ps[i][r];
          ad1[rg * 8 + hb + i] = pd[i][r];
        }
      }
    }
  }
}

// ---------------- CSR build ----------------
__global__ void k_scan1(const int* __restrict__ counts, int* __restrict__ offs,
                        int* __restrict__ bsums) {
  __shared__ int s[256];
  const int t = threadIdx.x;
  const int i = blockIdx.x * 256 + t;
  int v = (i < NN) ? counts[i] : 0;
  s[t] = v;
  __syncthreads();
  for (int off = 1; off < 256; off <<= 1) {
    int tv = (t >= off) ? s[t - off] : 0;
    __syncthreads();
    s[t] += tv;
    __syncthreads();
  }
  if (i < NN) offs[i] = s[t] - v;
  if (t == 255) bsums[blockIdx.x] = s[255];
}

__global__ void k_scan2(int* __restrict__ bsums, int nb) {
  __shared__ int s[512];
  const int t = threadIdx.x;
  int v = (t < nb) ? bsums[t] : 0;
  s[t] = v;
  __syncthreads();
  for (int off = 1; off < 512; off <<= 1) {
    int tv = (t >= off) ? s[t - off] : 0;
    __syncthreads();
    s[t] += tv;
    __syncthreads();
  }
  if (t < nb) bsums[t] = s[t] - v;
}

__global__ void k_scan3(int* __restrict__ offs, const int* __restrict__ bsums,
                        int* __restrict__ cursor) {
  const int i = blockIdx.x * 256 + threadIdx.x;
  if (i < NN) {
    int v = offs[i] + bsums[i >> 8];
    offs[i] = v;
    cursor[i] = v;
  }
  if (i == 0) offs[NN] = EE;
}

// ---------------- scatter: pure CSR permutation ----------------
__global__ void k_scatter(const int* __restrict__ ei, int* __restrict__ cursor,
                          int* __restrict__ esrc) {
  int e = blockIdx.x * 256 + threadIdx.x;
  if (e < EE) {
    int s = ei[e];
    int d = ei[EE + e];
    int p = atomicAdd(&cursor[d], 1);
    esrc[p] = s;
  }
}

// ---------------- agg1: wave-per-node gather + ELU, then MFMA GEMM2 + scores2 ------
// Per 64-edge chunk: each lane computes ALL 8 head-weights for its own edge
// (2x float4 as1 load + 8 exp, amortized 0.5 VALU/edge) and stores head-major
// into per-wave LDS (stride 68 floats -> conflict-free b128 broadcast reads).
// Inner loop per edge: 1 readlane (SALU) + 1 SGPR-based dwordx2 gather +
// unpack + 4 FMA. OOB chunk entries carry weight 0 / src 0 -> no predication.
__global__ __launch_bounds__(256) void k_agg1(const unsigned short* __restrict__ h1b,
                                              const float* __restrict__ as1,
                                              const float* __restrict__ ad1,
                                              const int* __restrict__ offs,
                                              const int* __restrict__ esrc,
                                              const float* __restrict__ b1,
                                              const unsigned short* __restrict__ W2thi,
                                              const unsigned short* __restrict__ W2tlo,
                                              const float* __restrict__ att_src2,
                                              const float* __restrict__ att_dst2,
                                              unsigned short* __restrict__ h2b,
                                              float* __restrict__ as2,
                                              float* __restrict__ ad2) {
  __shared__ float wl[4][8][68];                                  // 8704 B, banks spread by 4
  __shared__ __attribute__((aligned(16))) unsigned short o1hi[4][264];  // 528B rows
  __shared__ __attribute__((aligned(16))) unsigned short o1lo[4][264];
  const int t = threadIdx.x;
  const int lane = t & 63;
  const int w = t >> 6;
  const int n0 = blockIdx.x * 4;       // NN = 25000*4 exactly
  const int n = n0 + w;
  const int head = lane >> 3;
  const uint2* __restrict__ h1u2 = (const uint2*)h1b;
  const int start = offs[n], end = offs[n + 1];

  // per-node dst coefficients (wave-uniform address)
  const float4 dnA = *(const float4*)(ad1 + n * 8);
  const float4 dnB = *(const float4*)(ad1 + n * 8 + 4);
  const float adnh = head < 4 ? (head == 0 ? dnA.x : head == 1 ? dnA.y : head == 2 ? dnA.z : dnA.w)
                              : (head == 4 ? dnB.x : head == 5 ? dnB.y : head == 6 ? dnB.z : dnB.w);

  float z, a0, a1, a2, a3;
  {  // self loop
    float w0 = __expf(lrelu(as1[n * 8 + head] + adnh));
    uint2 q = h1u2[(size_t)n * 64 + lane];
    float f0, f1, f2, f3; unpack2(q.x, f0, f1); unpack2(q.y, f2, f3);
    z = w0; a0 = w0 * f0; a1 = w0 * f1; a2 = w0 * f2; a3 = w0 * f3;
  }
  for (int base = start; base < end; base += 64) {
    const int cnt = min(64, end - base);
    int s = 0;
    if (lane < cnt) s = esrc[base + lane];
    // all 8 head weights for this lane's edge
    const float4 avA = *(const float4*)(as1 + (size_t)s * 8);
    const float4 avB = *(const float4*)(as1 + (size_t)s * 8 + 4);
    float wv8[8];
    wv8[0] = __expf(lrelu(avA.x + dnA.x)); wv8[1] = __expf(lrelu(avA.y + dnA.y));
    wv8[2] = __expf(lrelu(avA.z + dnA.z)); wv8[3] = __expf(lrelu(avA.w + dnA.w));
    wv8[4] = __expf(lrelu(avB.x + dnB.x)); wv8[5] = __expf(lrelu(avB.y + dnB.y));
    wv8[6] = __expf(lrelu(avB.z + dnB.z)); wv8[7] = __expf(lrelu(avB.w + dnB.w));
    const bool act = lane < cnt;
#pragma unroll
    for (int h = 0; h < 8; ++h) wl[w][h][lane] = act ? wv8[h] : 0.f;
    // same-wave LDS write->read: compiler inserts lgkmcnt wait
#pragma unroll 2
    for (int jb = 0; jb < cnt; jb += 4) {
      const float4 wq = *(const float4*)&wl[w][head][jb];
      z += wq.x + wq.y + wq.z + wq.w;
      {
        const int sj = __builtin_amdgcn_readlane(s, jb);
        const uint2 q = h1u2[(size_t)sj * 64 + lane];
        float f0, f1, f2, f3; unpack2(q.x, f0, f1); unpack2(q.y, f2, f3);
        a0 += wq.x * f0; a1 += wq.x * f1; a2 += wq.x * f2; a3 += wq.x * f3;
      }
      {
        const int sj = __builtin_amdgcn_readlane(s, jb + 1);
        const uint2 q = h1u2[(size_t)sj * 64 + lane];
        float f0, f1, f2, f3; unpack2(q.x, f0, f1); unpack2(q.y, f2, f3);
        a0 += wq.y * f0; a1 += wq.y * f1; a2 += wq.y * f2; a3 += wq.y * f3;
      }
      {
        const int sj = __builtin_amdgcn_readlane(s, jb + 2);
        const uint2 q = h1u2[(size_t)sj * 64 + lane];
        float f0, f1, f2, f3; unpack2(q.x, f0, f1); unpack2(q.y, f2, f3);
        a0 += wq.z * f0; a1 += wq.z * f1; a2 += wq.z * f2; a3 += wq.z * f3;
      }
      {
        const int sj = __builtin_amdgcn_readlane(s, jb + 3);
        const uint2 q = h1u2[(size_t)sj * 64 + lane];
        float f0, f1, f2, f3; unpack2(q.x, f0, f1); unpack2(q.y, f2, f3);
        a0 += wq.w * f0; a1 += wq.w * f1; a2 += wq.w * f2; a3 += wq.w * f3;
      }
    }
  }
  // out1 = acc/z + b1, ELU; bf16 hi/lo split to LDS (channels 4*lane..+3)
  {
    const float zi = 1.0f / (z + 1e-16f);
    const float4 bb = *(const float4*)(b1 + 4 * lane);
    float v0 = a0 * zi + bb.x;
    float v1 = a1 * zi + bb.y;
    float v2 = a2 * zi + bb.z;
    float v3 = a3 * zi + bb.w;
    v0 = v0 > 0.f ? v0 : (__expf(v0) - 1.0f);
    v1 = v1 > 0.f ? v1 : (__expf(v1) - 1.0f);
    v2 = v2 > 0.f ? v2 : (__expf(v2) - 1.0f);
    v3 = v3 > 0.f ? v3 : (__expf(v3) - 1.0f);
    ushort4 hh, ll;
    hh.x = f2bf(v0); hh.y = f2bf(v1); hh.z = f2bf(v2); hh.w = f2bf(v3);
    ll.x = f2bf(v0 - bf2f(hh.x));
    ll.y = f2bf(v1 - bf2f(hh.y));
    ll.z = f2bf(v2 - bf2f(hh.z));
    ll.w = f2bf(v3 - bf2f(hh.w));
    *(ushort4*)&o1hi[w][4 * lane] = hh;
    *(ushort4*)&o1lo[w][4 * lane] = ll;
  }
  __syncthreads();
  if (w == 0) {
    // GEMM2: M=4 nodes x N=32 x K=256 on the matrix pipe (hi/lo split ~ f32)
    const int ml = lane & 15;
    const int quad = lane >> 4;
    const int mr = ml & 3;
    v4f acc[2];
    acc[0] = (v4f){0.f, 0.f, 0.f, 0.f};
    acc[1] = (v4f){0.f, 0.f, 0.f, 0.f};
#pragma unroll
    for (int kk = 0; kk < 8; ++kk) {
      const int k0 = kk * 32 + quad * 8;
      v8s ah = *(const v8s*)&o1hi[mr][k0];
      v8s al = *(const v8s*)&o1lo[mr][k0];
#pragma unroll
      for (int tt = 0; tt < 2; ++tt) {
        v8s bh = *(const v8s*)(W2thi + (size_t)(tt * 16 + ml) * 256 + k0);
        v8s bl = *(const v8s*)(W2tlo + (size_t)(tt * 16 + ml) * 256 + k0);
        acc[tt] = __builtin_amdgcn_mfma_f32_16x16x32_bf16(ah, bh, acc[tt], 0, 0, 0);
        acc[tt] = __builtin_amdgcn_mfma_f32_16x16x32_bf16(al, bh, acc[tt], 0, 0, 0);
        acc[tt] = __builtin_amdgcn_mfma_f32_16x16x32_bf16(ah, bl, acc[tt], 0, 0, 0);
      }
    }
    if (quad == 0) {
      const float s0 = att_src2[ml], s1 = att_src2[16 + ml];
      const float d0 = att_dst2[ml], d1 = att_dst2[16 + ml];
#pragma unroll
      for (int r = 0; r < 4; ++r) {
        const int nn = n0 + r;
        const float h0 = acc[0][r], h1v = acc[1][r];
        h2b[(size_t)nn * 32 + ml] = f2bf(h0);
        h2b[(size_t)nn * 32 + 16 + ml] = f2bf(h1v);
        float ps = h0 * s0 + h1v * s1;
        float pd = h0 * d0 + h1v * d1;
        ps += __shfl_xor(ps, 1, 64); ps += __shfl_xor(ps, 2, 64);
        ps += __shfl_xor(ps, 4, 64); ps += __shfl_xor(ps, 8, 64);
        pd += __shfl_xor(pd, 1, 64); pd += __shfl_xor(pd, 2, 64);
        pd += __shfl_xor(pd, 4, 64); pd += __shfl_xor(pd, 8, 64);
        if (ml == 0) { as2[nn] = ps; ad2[nn] = pd; }
      }
    }
  }
}

// ---------------- agg2: wave-per-node, LDS (src,weight) chunk, 4 edges/iter --------
// Per chunk: lane loads its edge + weight once; inner loop does one broadcast
// ds_read_b64 per edge (replaces 2 bpermutes) with no predication (OOB = 0,0.0).
__global__ __launch_bounds__(256) void k_agg2(const unsigned short* __restrict__ h2b,
                                              const float* __restrict__ as2,
                                              const float* __restrict__ ad2,
                                              const int* __restrict__ offs,
                                              const int* __restrict__ esrc,
                                              const float* __restrict__ b2,
                                              float* __restrict__ h3) {
  __shared__ int2 swl[4][64];   // per-wave (src, weight-bits)
  const int t = threadIdx.x;
  const int lane = t & 63;
  const int wv = t >> 6;
  const int n = blockIdx.x * 4 + wv;     // NN = 25000*4 exactly
  const int col = lane & 15;
  const int slot = lane >> 4;
  const unsigned int* __restrict__ h2u = (const unsigned int*)h2b;
  const int start = offs[n], end = offs[n + 1];
  const float adn = ad2[n];
  float z = 0.f, acc0 = 0.f, acc1 = 0.f;
  if (slot == 0) {   // self loop counted once
    float w0 = __expf(lrelu(as2[n] + adn));
    unsigned int q = h2u[(unsigned)(n * 16 + col)];
    float f0, f1; unpack2(q, f0, f1);
    z = w0; acc0 = w0 * f0; acc1 = w0 * f1;
  }
  for (int base = start; base < end; base += 64) {
    const int cnt = min(64, end - base);
    int s = 0; float wgt = 0.f;
    if (lane < cnt) {
      s = esrc[base + lane];
      wgt = __expf(lrelu(as2[s] + adn));
    }
    swl[wv][lane] = make_int2(s, __float_as_int(wgt));
    // same-wave LDS write->read: compiler inserts lgkmcnt wait
    const int jmax = (cnt + 3) >> 2;
#pragma unroll 4
    for (int j = 0; j < jmax; ++j) {
      const int2 p = swl[wv][4 * j + slot];
      const int sj = p.x;
      const float wj = __int_as_float(p.y);
      unsigned int q = h2u[(unsigned)(sj * 16 + col)];
      float f0, f1; unpack2(q, f0, f1);
      z += wj; acc0 += wj * f0; acc1 += wj * f1;
    }
  }
  // combine the 4 slot groups
  acc0 += __shfl_xor(acc0, 16, 64); acc0 += __shfl_xor(acc0, 32, 64);
  acc1 += __shfl_xor(acc1, 16, 64); acc1 += __shfl_xor(acc1, 32, 64);
  z    += __shfl_xor(z, 16, 64);    z    += __shfl_xor(z, 32, 64);
  if (slot == 0) {
    const float zi = 1.0f / (z + 1e-16f);
    float2 bb = *(const float2*)(b2 + 2 * col);
    float2 o;
    o.x = acc0 * zi + bb.x;
    o.y = acc1 * zi + bb.y;
    *(float2*)(h3 + (size_t)n * 32 + 2 * col) = o;
  }
}

// ---------------- pool + final linear (fused) ----------------
__global__ __launch_bounds__(256) void k_poolfin(const float* __restrict__ h3,
                                                 const int* __restrict__ batch,
                                                 const float* __restrict__ Wlin,
                                                 const float* __restrict__ blin,
                                                 float* __restrict__ out) {
  __shared__ int bounds[2];
  __shared__ float red[8][33];
  __shared__ float mean[32];
  const int g = blockIdx.x;
  const int t = threadIdx.x;
  if (t < 2) {
    int target = g + t;
    int lo = 0, hi = NN;
    while (lo < hi) { int mid = (lo + hi) >> 1; if (batch[mid] < target) lo = mid + 1; else hi = mid; }
    bounds[t] = lo;
  }
  __syncthreads();
  const int lo = bounds[0], hi = bounds[1];
  const int rr = t >> 5, c = t & 31;
  float a = 0.f;
  for (int r = lo + rr; r < hi; r += 8) a += h3[(size_t)r * 32 + c];
  red[rr][c] = a;
  __syncthreads();
  if (rr == 0) {
    float s = 0.f;
#pragma unroll
    for (int i = 0; i < 8; ++i) s += red[i][c];
    float ct = (float)(hi - lo);
    ct = ct > 1.f ? ct : 1.f;
    mean[c] = s / ct;
  }
  __syncthreads();
  if (t < NC) {
    float acc = 0.f;
#pragma unroll
    for (int cc = 0; cc < 32; ++cc) acc += mean[cc] * Wlin[cc * NC + t];
    out[g * NC + t] = acc + blin[t];
  }
}

extern "C" void kernel_launch(void* const* d_in, const int* in_sizes, int n_in,
                              void* d_out, int out_size, void* d_ws, size_t ws_size,
                              hipStream_t stream) {
  const float* x        = (const float*)d_in[0];
  const int*   ei       = (const int*)d_in[1];
  const int*   batch    = (const int*)d_in[2];
  const float* W1       = (const float*)d_in[3];
  const float* att_src1 = (const float*)d_in[4];
  const float* att_dst1 = (const float*)d_in[5];
  const float* b1       = (const float*)d_in[6];
  const float* W2       = (const float*)d_in[7];
  const float* att_src2 = (const float*)d_in[8];
  const float* att_dst2 = (const float*)d_in[9];
  const float* b2       = (const float*)d_in[10];
  const float* Wlin     = (const float*)d_in[11];
  const float* blin     = (const float*)d_in[12];
  float* out = (float*)d_out;
  char* ws = (char*)d_ws;

  // workspace layout (bytes); peak ~98.1 MB
  unsigned short* h1b   = (unsigned short*)(ws + 0);         // 51,200,000
  unsigned short* xb    = (unsigned short*)(ws + 51200000);  // 25,600,000 (dead after gemm1)
  float* h3     = (float*)(ws + 51200000);                   // 12,800,000 overlay on xb
  float* as1    = (float*)(ws + 76800000);                   // 3,200,000
  float* ad1    = (float*)(ws + 80000000);                   // 3,200,000
  int* counts   = (int*)(ws + 83200000);                     // 400,000
  int* offs     = (int*)(ws + 83600000);                     // 400,004 (+pad)
  int* cursor   = (int*)(ws + 84000256);                     // 400,000
  int* esrc     = (int*)(ws + 84400256);                     // 6,400,000
  int* bsums    = (int*)(ws + 90800256);                     // 2,048 (pad)
  unsigned short* h2b   = (unsigned short*)(ws + 90802304);  // 6,400,000
  float* as2    = (float*)(ws + 97202304);                   // 400,000
  float* ad2    = (float*)(ws + 97602304);                   // 400,000
  unsigned short* W1tg  = (unsigned short*)(ws + 98002304);  // 65,536
  unsigned short* W2thi = (unsigned short*)(ws + 98067840);  // 16,384
  unsigned short* W2tlo = (unsigned short*)(ws + 98084224);  // 16,384

  const int nb_scan = (NN + 255) / 256;  // 391

  hipMemsetAsync(counts, 0, NN * sizeof(int), stream);
  k_prepx<<<12500, 256, 0, stream>>>(x, xb, ei, counts);
  k_prep<<<256, 128, 0, stream>>>(W1, W1tg);
  k_prepw2<<<32, 256, 0, stream>>>(W2, W2thi, W2tlo);

  dim3 g1((NN + 63) / 64, 2);
  k_gemm1<<<g1, 256, 0, stream>>>(xb, W1tg, att_src1, att_dst1, h1b, as1, ad1);

  k_scan1<<<nb_scan, 256, 0, stream>>>(counts, offs, bsums);
  k_scan2<<<1, 512, 0, stream>>>(bsums, nb_scan);
  k_scan3<<<nb_scan, 256, 0, stream>>>(offs, bsums, cursor);
  k_scatter<<<(EE + 255) / 256, 256, 0, stream>>>(ei, cursor, esrc);

  k_agg1<<<NN / 4, 256, 0, stream>>>(h1b, as1, ad1, offs, esrc, b1, W2thi, W2tlo,
                                     att_src2, att_dst2, h2b, as2, ad2);

  k_agg2<<<NN / 4, 256, 0, stream>>>(h2b, as2, ad2, offs, esrc, b2, h3);
  k_poolfin<<<GG, 256, 0, stream>>>(h3, batch, Wlin, blin, out);
}

// Round 3
// 622.447 us; speedup vs baseline: 1.0778x; 1.0217x over previous
//
#include <hip/hip_runtime.h>
#include <cstdint>

#define NN 100000
#define EE 1600000
#define GG 64
#define FIN 128
#define HC 256      // H*C for layer 1
#define NC 10

typedef short v8s __attribute__((ext_vector_type(8)));
typedef float v4f __attribute__((ext_vector_type(4)));

static __device__ __forceinline__ float lrelu(float x) { return x > 0.f ? x : 0.2f * x; }
static __device__ __forceinline__ float bf2f(unsigned short b) {
  return __uint_as_float(((unsigned int)b) << 16);
}
static __device__ __forceinline__ unsigned short f2bf(float f) {
  unsigned int u = __float_as_uint(f);
  unsigned int r = (u + 0x7FFFu + ((u >> 16) & 1u)) >> 16;
  return (unsigned short)r;
}
static __device__ __forceinline__ void unpack2(unsigned int u, float& f0, float& f1) {
  f0 = __uint_as_float(u << 16);          // even channel (lo ushort)
  f1 = __uint_as_float(u & 0xFFFF0000u);  // odd channel (hi ushort)
}

// ---------------- prepx: x -> bf16 (streamed) + fused edge count ----------------
// counts zeroed by hipMemsetAsync before this kernel; 3.2M threads >= EE.
__global__ __launch_bounds__(256) void k_prepx(const float* __restrict__ x,
                                               unsigned short* __restrict__ xb,
                                               const int* __restrict__ ei,
                                               int* __restrict__ counts) {
  const int idx = blockIdx.x * 256 + threadIdx.x;
  const int i4 = idx * 4;                       // 12500*256*4 == 12.8M exact
  float4 v = *(const float4*)(x + i4);
  ushort4 u;
  u.x = f2bf(v.x); u.y = f2bf(v.y); u.z = f2bf(v.z); u.w = f2bf(v.w);
  *(ushort4*)(xb + i4) = u;
  if (idx < EE) atomicAdd(&counts[ei[EE + idx]], 1);
}

// ---------------- prep: W1 -> bf16 transposed [n][k] ----------------
__global__ void k_prep(const float* __restrict__ W1, unsigned short* __restrict__ W1tg) {
  const int b = blockIdx.x, t = threadIdx.x;
  if (t < 128) W1tg[b * 128 + t] = f2bf(W1[t * HC + b]);
}

// ---------------- prep: W2 -> bf16 hi/lo split, transposed [32][256] ----------------
__global__ void k_prepw2(const float* __restrict__ W2,
                         unsigned short* __restrict__ W2thi,
                         unsigned short* __restrict__ W2tlo) {
  const int b = blockIdx.x;    // output channel 0..31
  const int t = threadIdx.x;   // k 0..255
  float w = W2[t * 32 + b];
  unsigned short hi = f2bf(w);
  W2thi[b * 256 + t] = hi;
  W2tlo[b * 256 + t] = f2bf(w - bf2f(hi));
}

// ---------------- GEMM1 (bf16 MFMA, LDS-free) + fused scores1 ----------------
__global__ __launch_bounds__(256) void k_gemm1(const unsigned short* __restrict__ xb,
                                               const unsigned short* __restrict__ W1tg,
                                               const float* __restrict__ att_src1,
                                               const float* __restrict__ att_dst1,
                                               unsigned short* __restrict__ h1b,
                                               float* __restrict__ as1,
                                               float* __restrict__ ad1) {
  const int t = threadIdx.x;
  const int m0 = blockIdx.x * 64;
  const int n0 = blockIdx.y * 128;
  const int hb = blockIdx.y * 4;       // head base of this column half
  const int lane = t & 63;
  const int wm = t >> 6;               // wave -> m sub-tile
  const int ml = lane & 15;
  const int quad = lane >> 4;
  int row = m0 + wm * 16 + ml; if (row >= NN) row = NN - 1;
  v4f acc[8];
#pragma unroll
  for (int tt = 0; tt < 8; ++tt) acc[tt] = (v4f){0.f, 0.f, 0.f, 0.f};
#pragma unroll
  for (int kk = 0; kk < 4; ++kk) {
    const int k0 = kk * 32 + quad * 8;
    v8s a = *(const v8s*)(xb + (size_t)row * FIN + k0);
#pragma unroll
    for (int tt = 0; tt < 8; ++tt) {
      v8s b = *(const v8s*)(W1tg + (size_t)(n0 + tt * 16 + ml) * FIN + k0);
      acc[tt] = __builtin_amdgcn_mfma_f32_16x16x32_bf16(a, b, acc[tt], 0, 0, 0);
    }
  }
  // h1b store (C layout: row=quad*4+r, col=tt*16+ml)
#pragma unroll
  for (int tt = 0; tt < 8; ++tt) {
#pragma unroll
    for (int r = 0; r < 4; ++r) {
      int rg = m0 + wm * 16 + quad * 4 + r;
      if (rg < NN) h1b[(size_t)rg * HC + n0 + tt * 16 + ml] = f2bf(acc[tt][r]);
    }
  }
  // fused scores1
  float ps[4][4], pd[4][4];
#pragma unroll
  for (int i = 0; i < 4; ++i)
#pragma unroll
    for (int r = 0; r < 4; ++r) { ps[i][r] = 0.f; pd[i][r] = 0.f; }
#pragma unroll
  for (int i = 0; i < 4; ++i) {
#pragma unroll
    for (int half = 0; half < 2; ++half) {
      const int tt = 2 * i + half;
      const float a_s = att_src1[(hb + i) * 32 + half * 16 + ml];
      const float a_d = att_dst1[(hb + i) * 32 + half * 16 + ml];
#pragma unroll
      for (int r = 0; r < 4; ++r) {
        ps[i][r] += acc[tt][r] * a_s;
        pd[i][r] += acc[tt][r] * a_d;
      }
    }
  }
#pragma unroll
  for (int i = 0; i < 4; ++i) {
#pragma unroll
    for (int r = 0; r < 4; ++r) {
      float s = ps[i][r], d = pd[i][r];
      s += __shfl_xor(s, 1, 64); s += __shfl_xor(s, 2, 64);
      s += __shfl_xor(s, 4, 64); s += __shfl_xor(s, 8, 64);
      d += __shfl_xor(d, 1, 64); d += __shfl_xor(d, 2, 64);
      d += __shfl_xor(d, 4, 64); d += __shfl_xor(d, 8, 64);
      ps[i][r] = s; pd[i][r] = d;
    }
  }
  if (ml == 0) {
#pragma unroll
    for (int r = 0; r < 4; ++r) {
      int rg = m0 + wm * 16 + quad * 4 + r;
      if (rg < NN) {
#pragma unroll
        for (int i = 0; i < 4; ++i) {
          as1[rg * 8 + hb + i] = ps[i][r];
          ad1[rg * 8 + hb + i] = pd[i][r];
        }
      }
    }
  }
}

// ---------------- CSR build ----------------
__global__ void k_scan1(const int* __restrict__ counts, int* __restrict__ offs,
                        int* __restrict__ bsums) {
  __shared__ int s[256];
  const int t = threadIdx.x;
  const int i = blockIdx.x * 256 + t;
  int v = (i < NN) ? counts[i] : 0;
  s[t] = v;
  __syncthreads();
  for (int off = 1; off < 256; off <<= 1) {
    int tv = (t >= off) ? s[t - off] : 0;
    __syncthreads();
    s[t] += tv;
    __syncthreads();
  }
  if (i < NN) offs[i] = s[t] - v;
  if (t == 255) bsums[blockIdx.x] = s[255];
}

__global__ void k_scan2(int* __restrict__ bsums, int nb) {
  __shared__ int s[512];
  const int t = threadIdx.x;
  int v = (t < nb) ? bsums[t] : 0;
  s[t] = v;
  __syncthreads();
  for (int off = 1; off < 512; off <<= 1) {
    int tv = (t >= off) ? s[t - off] : 0;
    __syncthreads();
    s[t] += tv;
    __syncthreads();
  }
  if (t < nb) bsums[t] = s[t] - v;
}

__global__ void k_scan3(int* __restrict__ offs, const int* __restrict__ bsums,
                        int* __restrict__ cursor) {
  const int i = blockIdx.x * 256 + threadIdx.x;
  if (i < NN) {
    int v = offs[i] + bsums[i >> 8];
    offs[i] = v;
    cursor[i] = v;
  }
  if (i == 0) offs[NN] = EE;
}

// ---------------- scatter: pure CSR permutation ----------------
__global__ void k_scatter(const int* __restrict__ ei, int* __restrict__ cursor,
                          int* __restrict__ esrc) {
  int e = blockIdx.x * 256 + threadIdx.x;
  if (e < EE) {
    int s = ei[e];
    int d = ei[EE + e];
    int p = atomicAdd(&cursor[d], 1);
    esrc[p] = s;
  }
}

// ---------------- agg1: wave-per-node gather + ELU, then MFMA GEMM2 + scores2 ------
// Chunk = 32 edges. Weight compute split across half-waves: lanes 0-31 compute
// heads 0-3, lanes 32-63 heads 4-7 of the SAME 32 edges (1 dwordx4 gather +
// 4 exp per lane per chunk). Node id / offs / inner-loop esrc reads are
// readfirstlane-uniform -> SMEM (s_load), off the VALU pipe. Gathers issued in
// explicit 8-deep batches for latency hiding. Padded edges (up to cnt4) carry
// weight 0; esrc has a 64B zeroed tail so padded sj stays in-bounds.
__global__ __launch_bounds__(256) void k_agg1(const unsigned short* __restrict__ h1b,
                                              const float* __restrict__ as1,
                                              const float* __restrict__ ad1,
                                              const int* __restrict__ offs,
                                              const int* __restrict__ esrc,
                                              const float* __restrict__ b1,
                                              const unsigned short* __restrict__ W2thi,
                                              const unsigned short* __restrict__ W2tlo,
                                              const float* __restrict__ att_src2,
                                              const float* __restrict__ att_dst2,
                                              unsigned short* __restrict__ h2b,
                                              float* __restrict__ as2,
                                              float* __restrict__ ad2) {
  __shared__ float wl[4][8][36];                                       // stride 36: bank (4h+j)&31
  __shared__ __attribute__((aligned(16))) unsigned short o1hi[4][272]; // 544B rows
  __shared__ __attribute__((aligned(16))) unsigned short o1lo[4][272];
  const int t = threadIdx.x;
  const int lane = t & 63;
  const int w = t >> 6;
  const int n0 = blockIdx.x * 4;       // NN = 25000*4 exactly
  const int nu = __builtin_amdgcn_readfirstlane(n0 + w);   // SGPR node id
  const int head = lane >> 3;
  const uint2* __restrict__ h1u2 = (const uint2*)h1b;
  const int start = offs[nu], end = offs[nu + 1];          // s_load
  const float4 dnA = *(const float4*)(ad1 + (size_t)nu * 8);      // s_load_dwordx4
  const float4 dnB = *(const float4*)(ad1 + (size_t)nu * 8 + 4);
  const float4 dn4 = (lane & 32) ? dnB : dnA;

  float z, a0, a1, a2, a3;
  {  // self loop
    float w0 = __expf(lrelu(as1[nu * 8 + head] + ad1[nu * 8 + head]));
    uint2 q = h1u2[(size_t)nu * 64 + lane];
    float f0, f1, f2, f3; unpack2(q.x, f0, f1); unpack2(q.y, f2, f3);
    z = w0; a0 = w0 * f0; a1 = w0 * f1; a2 = w0 * f2; a3 = w0 * f3;
  }
  for (int base = start; base < end; base += 32) {
    const int cnt = min(32, end - base);
    const int l5 = lane & 31;
    int s = 0;
    if (l5 < cnt) s = esrc[base + l5];
    const int hb4 = (lane >> 5) << 2;    // 0 or 4
    const float4 av = *(const float4*)(as1 + (size_t)s * 8 + hb4);
    float w0 = __expf(lrelu(av.x + dn4.x));
    float w1 = __expf(lrelu(av.y + dn4.y));
    float w2 = __expf(lrelu(av.z + dn4.z));
    float w3 = __expf(lrelu(av.w + dn4.w));
    const bool act = l5 < cnt;
    wl[w][hb4 + 0][l5] = act ? w0 : 0.f;
    wl[w][hb4 + 1][l5] = act ? w1 : 0.f;
    wl[w][hb4 + 2][l5] = act ? w2 : 0.f;
    wl[w][hb4 + 3][l5] = act ? w3 : 0.f;
    // same-wave LDS write->read: compiler inserts lgkmcnt wait
    const int cnt4 = (cnt + 3) & ~3;
    int jb = 0;
    for (; jb + 8 <= cnt4; jb += 8) {
      uint2 q[8];
#pragma unroll
      for (int u = 0; u < 8; ++u) {
        const int sj = esrc[base + jb + u];            // uniform -> s_load
        q[u] = h1u2[(size_t)sj * 64 + lane];
      }
      const float4 wq0 = *(const float4*)&wl[w][head][jb];
      const float4 wq1 = *(const float4*)&wl[w][head][jb + 4];
      z += ((wq0.x + wq0.y) + (wq0.z + wq0.w)) + ((wq1.x + wq1.y) + (wq1.z + wq1.w));
      float f0, f1, f2, f3;
      unpack2(q[0].x, f0, f1); unpack2(q[0].y, f2, f3);
      a0 += wq0.x * f0; a1 += wq0.x * f1; a2 += wq0.x * f2; a3 += wq0.x * f3;
      unpack2(q[1].x, f0, f1); unpack2(q[1].y, f2, f3);
      a0 += wq0.y * f0; a1 += wq0.y * f1; a2 += wq0.y * f2; a3 += wq0.y * f3;
      unpack2(q[2].x, f0, f1); unpack2(q[2].y, f2, f3);
      a0 += wq0.z * f0; a1 += wq0.z * f1; a2 += wq0.z * f2; a3 += wq0.z * f3;
      unpack2(q[3].x, f0, f1); unpack2(q[3].y, f2, f3);
      a0 += wq0.w * f0; a1 += wq0.w * f1; a2 += wq0.w * f2; a3 += wq0.w * f3;
      unpack2(q[4].x, f0, f1); unpack2(q[4].y, f2, f3);
      a0 += wq1.x * f0; a1 += wq1.x * f1; a2 += wq1.x * f2; a3 += wq1.x * f3;
      unpack2(q[5].x, f0, f1); unpack2(q[5].y, f2, f3);
      a0 += wq1.y * f0; a1 += wq1.y * f1; a2 += wq1.y * f2; a3 += wq1.y * f3;
      unpack2(q[6].x, f0, f1); unpack2(q[6].y, f2, f3);
      a0 += wq1.z * f0; a1 += wq1.z * f1; a2 += wq1.z * f2; a3 += wq1.z * f3;
      unpack2(q[7].x, f0, f1); unpack2(q[7].y, f2, f3);
      a0 += wq1.w * f0; a1 += wq1.w * f1; a2 += wq1.w * f2; a3 += wq1.w * f3;
    }
    if (jb < cnt4) {   // 4-edge tail batch
      uint2 q[4];
#pragma unroll
      for (int u = 0; u < 4; ++u) {
        const int sj = esrc[base + jb + u];            // uniform -> s_load
        q[u] = h1u2[(size_t)sj * 64 + lane];
      }
      const float4 wq0 = *(const float4*)&wl[w][head][jb];
      z += (wq0.x + wq0.y) + (wq0.z + wq0.w);
      float f0, f1, f2, f3;
      unpack2(q[0].x, f0, f1); unpack2(q[0].y, f2, f3);
      a0 += wq0.x * f0; a1 += wq0.x * f1; a2 += wq0.x * f2; a3 += wq0.x * f3;
      unpack2(q[1].x, f0, f1); unpack2(q[1].y, f2, f3);
      a0 += wq0.y * f0; a1 += wq0.y * f1; a2 += wq0.y * f2; a3 += wq0.y * f3;
      unpack2(q[2].x, f0, f1); unpack2(q[2].y, f2, f3);
      a0 += wq0.z * f0; a1 += wq0.z * f1; a2 += wq0.z * f2; a3 += wq0.z * f3;
      unpack2(q[3].x, f0, f1); unpack2(q[3].y, f2, f3);
      a0 += wq0.w * f0; a1 += wq0.w * f1; a2 += wq0.w * f2; a3 += wq0.w * f3;
    }
  }
  // out1 = acc/z + b1, ELU; bf16 hi/lo split to LDS (channels 4*lane..+3)
  {
    const float zi = 1.0f / (z + 1e-16f);
    const float4 bb = *(const float4*)(b1 + 4 * lane);
    float v0 = a0 * zi + bb.x;
    float v1 = a1 * zi + bb.y;
    float v2 = a2 * zi + bb.z;
    float v3 = a3 * zi + bb.w;
    v0 = v0 > 0.f ? v0 : (__expf(v0) - 1.0f);
    v1 = v1 > 0.f ? v1 : (__expf(v1) - 1.0f);
    v2 = v2 > 0.f ? v2 : (__expf(v2) - 1.0f);
    v3 = v3 > 0.f ? v3 : (__expf(v3) - 1.0f);
    ushort4 hh, ll;
    hh.x = f2bf(v0); hh.y = f2bf(v1); hh.z = f2bf(v2); hh.w = f2bf(v3);
    ll.x = f2bf(v0 - bf2f(hh.x));
    ll.y = f2bf(v1 - bf2f(hh.y));
    ll.z = f2bf(v2 - bf2f(hh.z));
    ll.w = f2bf(v3 - bf2f(hh.w));
    *(ushort4*)&o1hi[w][4 * lane] = hh;
    *(ushort4*)&o1lo[w][4 * lane] = ll;
  }
  __syncthreads();
  if (w == 0) {
    // GEMM2: M=4 nodes x N=32 x K=256 on the matrix pipe (hi/lo split ~ f32)
    const int ml = lane & 15;
    const int quad = lane >> 4;
    const int mr = ml & 3;
    v4f acc[2];
    acc[0] = (v4f){0.f, 0.f, 0.f, 0.f};
    acc[1] = (v4f){0.f, 0.f, 0.f, 0.f};
#pragma unroll
    for (int kk = 0; kk < 8; ++kk) {
      const int k0 = kk * 32 + quad * 8;
      v8s ah = *(const v8s*)&o1hi[mr][k0];
      v8s al = *(const v8s*)&o1lo[mr][k0];
#pragma unroll
      for (int tt = 0; tt < 2; ++tt) {
        v8s bh = *(const v8s*)(W2thi + (size_t)(tt * 16 + ml) * 256 + k0);
        v8s bl = *(const v8s*)(W2tlo + (size_t)(tt * 16 + ml) * 256 + k0);
        acc[tt] = __builtin_amdgcn_mfma_f32_16x16x32_bf16(ah, bh, acc[tt], 0, 0, 0);
        acc[tt] = __builtin_amdgcn_mfma_f32_16x16x32_bf16(al, bh, acc[tt], 0, 0, 0);
        acc[tt] = __builtin_amdgcn_mfma_f32_16x16x32_bf16(ah, bl, acc[tt], 0, 0, 0);
      }
    }
    if (quad == 0) {
      const float s0 = att_src2[ml], s1 = att_src2[16 + ml];
      const float d0 = att_dst2[ml], d1 = att_dst2[16 + ml];
#pragma unroll
      for (int r = 0; r < 4; ++r) {
        const int nn = n0 + r;
        const float h0 = acc[0][r], h1v = acc[1][r];
        h2b[(size_t)nn * 32 + ml] = f2bf(h0);
        h2b[(size_t)nn * 32 + 16 + ml] = f2bf(h1v);
        float ps = h0 * s0 + h1v * s1;
        float pd = h0 * d0 + h1v * d1;
        ps += __shfl_xor(ps, 1, 64); ps += __shfl_xor(ps, 2, 64);
        ps += __shfl_xor(ps, 4, 64); ps += __shfl_xor(ps, 8, 64);
        pd += __shfl_xor(pd, 1, 64); pd += __shfl_xor(pd, 2, 64);
        pd += __shfl_xor(pd, 4, 64); pd += __shfl_xor(pd, 8, 64);
        if (ml == 0) { as2[nn] = ps; ad2[nn] = pd; }
      }
    }
  }
}

// ---------------- agg2: wave-per-node, LDS (src,weight) chunk, 8 edges in flight ---
// Slot group handles edges 8j+slot and 8j+4+slot: two independent loads per
// iteration, no per-edge predication (OOB swl entries are (0, 0.0)).
__global__ __launch_bounds__(256) void k_agg2(const unsigned short* __restrict__ h2b,
                                              const float* __restrict__ as2,
                                              const float* __restrict__ ad2,
                                              const int* __restrict__ offs,
                                              const int* __restrict__ esrc,
                                              const float* __restrict__ b2,
                                              float* __restrict__ h3) {
  __shared__ int2 swl[4][64];   // per-wave (src, weight-bits)
  const int t = threadIdx.x;
  const int lane = t & 63;
  const int wv = t >> 6;
  const int n = __builtin_amdgcn_readfirstlane(blockIdx.x * 4 + wv);  // NN = 25000*4
  const int col = lane & 15;
  const int slot = lane >> 4;
  const unsigned int* __restrict__ h2u = (const unsigned int*)h2b;
  const int start = offs[n], end = offs[n + 1];   // s_load
  const float adn = ad2[n];                       // s_load
  float z = 0.f, acc0 = 0.f, acc1 = 0.f;
  if (slot == 0) {   // self loop counted once
    float w0 = __expf(lrelu(as2[n] + adn));
    unsigned int q = h2u[(unsigned)(n * 16 + col)];
    float f0, f1; unpack2(q, f0, f1);
    z = w0; acc0 = w0 * f0; acc1 = w0 * f1;
  }
  for (int base = start; base < end; base += 64) {
    const int cnt = min(64, end - base);
    int s = 0; float wgt = 0.f;
    if (lane < cnt) {
      s = esrc[base + lane];
      wgt = __expf(lrelu(as2[s] + adn));
    }
    swl[wv][lane] = make_int2(s, __float_as_int(wgt));
    // same-wave LDS write->read: compiler inserts lgkmcnt wait
    const int nit = (cnt + 7) >> 3;
#pragma unroll 2
    for (int j = 0; j < nit; ++j) {
      const int2 p0 = swl[wv][8 * j + slot];
      const int2 p1 = swl[wv][8 * j + 4 + slot];
      const unsigned int q0 = h2u[(unsigned)(p0.x * 16 + col)];
      const unsigned int q1 = h2u[(unsigned)(p1.x * 16 + col)];
      const float wj0 = __int_as_float(p0.y);
      const float wj1 = __int_as_float(p1.y);
      float f0, f1, g0, g1;
      unpack2(q0, f0, f1); unpack2(q1, g0, g1);
      z += wj0 + wj1;
      acc0 += wj0 * f0; acc0 += wj1 * g0;
      acc1 += wj0 * f1; acc1 += wj1 * g1;
    }
  }
  // combine the 4 slot groups
  acc0 += __shfl_xor(acc0, 16, 64); acc0 += __shfl_xor(acc0, 32, 64);
  acc1 += __shfl_xor(acc1, 16, 64); acc1 += __shfl_xor(acc1, 32, 64);
  z    += __shfl_xor(z, 16, 64);    z    += __shfl_xor(z, 32, 64);
  if (slot == 0) {
    const float zi = 1.0f / (z + 1e-16f);
    float2 bb = *(const float2*)(b2 + 2 * col);
    float2 o;
    o.x = acc0 * zi + bb.x;
    o.y = acc1 * zi + bb.y;
    *(float2*)(h3 + (size_t)n * 32 + 2 * col) = o;
  }
}

// ---------------- pool + final linear (fused) ----------------
__global__ __launch_bounds__(256) void k_poolfin(const float* __restrict__ h3,
                                                 const int* __restrict__ batch,
                                                 const float* __restrict__ Wlin,
                                                 const float* __restrict__ blin,
                                                 float* __restrict__ out) {
  __shared__ int bounds[2];
  __shared__ float red[8][33];
  __shared__ float mean[32];
  const int g = blockIdx.x;
  const int t = threadIdx.x;
  if (t < 2) {
    int target = g + t;
    int lo = 0, hi = NN;
    while (lo < hi) { int mid = (lo + hi) >> 1; if (batch[mid] < target) lo = mid + 1; else hi = mid; }
    bounds[t] = lo;
  }
  __syncthreads();
  const int lo = bounds[0], hi = bounds[1];
  const int rr = t >> 5, c = t & 31;
  float a = 0.f;
  for (int r = lo + rr; r < hi; r += 8) a += h3[(size_t)r * 32 + c];
  red[rr][c] = a;
  __syncthreads();
  if (rr == 0) {
    float s = 0.f;
#pragma unroll
    for (int i = 0; i < 8; ++i) s += red[i][c];
    float ct = (float)(hi - lo);
    ct = ct > 1.f ? ct : 1.f;
    mean[c] = s / ct;
  }
  __syncthreads();
  if (t < NC) {
    float acc = 0.f;
#pragma unroll
    for (int cc = 0; cc < 32; ++cc) acc += mean[cc] * Wlin[cc * NC + t];
    out[g * NC + t] = acc + blin[t];
  }
}

extern "C" void kernel_launch(void* const* d_in, const int* in_sizes, int n_in,
                              void* d_out, int out_size, void* d_ws, size_t ws_size,
                              hipStream_t stream) {
  const float* x        = (const float*)d_in[0];
  const int*   ei       = (const int*)d_in[1];
  const int*   batch    = (const int*)d_in[2];
  const float* W1       = (const float*)d_in[3];
  const float* att_src1 = (const float*)d_in[4];
  const float* att_dst1 = (const float*)d_in[5];
  const float* b1       = (const float*)d_in[6];
  const float* W2       = (const float*)d_in[7];
  const float* att_src2 = (const float*)d_in[8];
  const float* att_dst2 = (const float*)d_in[9];
  const float* b2       = (const float*)d_in[10];
  const float* Wlin     = (const float*)d_in[11];
  const float* blin     = (const float*)d_in[12];
  float* out = (float*)d_out;
  char* ws = (char*)d_ws;

  // workspace layout (bytes); peak ~98.1 MB
  unsigned short* h1b   = (unsigned short*)(ws + 0);         // 51,200,000
  unsigned short* xb    = (unsigned short*)(ws + 51200000);  // 25,600,000 (dead after gemm1)
  float* h3     = (float*)(ws + 51200000);                   // 12,800,000 overlay on xb
  float* as1    = (float*)(ws + 76800000);                   // 3,200,000
  float* ad1    = (float*)(ws + 80000000);                   // 3,200,000
  int* counts   = (int*)(ws + 83200000);                     // 400,000
  int* offs     = (int*)(ws + 83600000);                     // 400,004 (+pad)
  int* cursor   = (int*)(ws + 84000256);                     // 400,000
  int* esrc     = (int*)(ws + 84400256);                     // 6,400,000 + 64B zero pad
  int* bsums    = (int*)(ws + 90800320);                     // 1,564 (+pad)
  unsigned short* h2b   = (unsigned short*)(ws + 90801920);  // 6,400,000
  float* as2    = (float*)(ws + 97201920);                   // 400,000
  float* ad2    = (float*)(ws + 97601920);                   // 400,000
  unsigned short* W1tg  = (unsigned short*)(ws + 98001920);  // 65,536
  unsigned short* W2thi = (unsigned short*)(ws + 98067456);  // 16,384
  unsigned short* W2tlo = (unsigned short*)(ws + 98083840);  // 16,384

  const int nb_scan = (NN + 255) / 256;  // 391

  hipMemsetAsync(counts, 0, NN * sizeof(int), stream);
  hipMemsetAsync(ws + 90800256, 0, 64, stream);   // esrc tail pad (padded-batch reads)
  k_prepx<<<12500, 256, 0, stream>>>(x, xb, ei, counts);
  k_prep<<<256, 128, 0, stream>>>(W1, W1tg);
  k_prepw2<<<32, 256, 0, stream>>>(W2, W2thi, W2tlo);

  dim3 g1((NN + 63) / 64, 2);
  k_gemm1<<<g1, 256, 0, stream>>>(xb, W1tg, att_src1, att_dst1, h1b, as1, ad1);

  k_scan1<<<nb_scan, 256, 0, stream>>>(counts, offs, bsums);
  k_scan2<<<1, 512, 0, stream>>>(bsums, nb_scan);
  k_scan3<<<nb_scan, 256, 0, stream>>>(offs, bsums, cursor);
  k_scatter<<<(EE + 255) / 256, 256, 0, stream>>>(ei, cursor, esrc);

  k_agg1<<<NN / 4, 256, 0, stream>>>(h1b, as1, ad1, offs, esrc, b1, W2thi, W2tlo,
                                     att_src2, att_dst2, h2b, as2, ad2);

  k_agg2<<<NN / 4, 256, 0, stream>>>(h2b, as2, ad2, offs, esrc, b2, h3);
  k_poolfin<<<GG, 256, 0, stream>>>(h3, batch, Wlin, blin, out);
}